// Round 1
// baseline (735.879 us; speedup 1.0000x reference)
//
#include <hip/hip_runtime.h>
#include <math.h>

// LinkPredictor fused MLP for MI355X (gfx950).
// layers: X0=[concat(z[row],z[col])] (E,512) -> relu(X0 W1^T+b1) (E,512)
//         -> relu(X1 W2^T+b2) (E,256) -> relu(X2 W3^T+b3) (E,256)
//         -> sigmoid(X3 W4^T+b4) (E,1)
// Strategy: block = 128 edges, fully fused, f16 MFMA 16x16x32, activations in
// LDS (aliased X0/X1/X2 with barriers), weights pre-repacked into per-lane
// fragment streams in d_ws (coalesced dwordx4 loads, L2-resident).

typedef _Float16 f16x8 __attribute__((ext_vector_type(8)));
typedef _Float16 f16x4 __attribute__((ext_vector_type(4)));
typedef float    f32x4 __attribute__((ext_vector_type(4)));

#define W1E (512*512)
#define W2E (256*512)
#define W3E (256*256)
#define WTOT (W1E+W2E+W3E)

// Repack W[N][K] fp32 -> f16 fragment stream:
// dst[((ntile*(K/32)+ktile)*64 + lane)*8 + j] = W[ntile*16+(lane&15)][ktile*32+(lane>>4)*8+j]
__global__ void repack_w(const float* __restrict__ W1, const float* __restrict__ W2,
                         const float* __restrict__ W3, _Float16* __restrict__ wout) {
  int t = blockIdx.x * 256 + threadIdx.x;
  if (t >= WTOT) return;
  const float* src; _Float16* dst; int K, idx;
  if (t < W1E)            { src = W1; K = 512; idx = t;             dst = wout; }
  else if (t < W1E + W2E) { src = W2; K = 512; idx = t - W1E;       dst = wout + W1E; }
  else                    { src = W3; K = 256; idx = t - (W1E+W2E); dst = wout + W1E + W2E; }
  int j    = idx & 7;
  int lane = (idx >> 3) & 63;
  int rest = idx >> 9;              // = ntile*(K/32) + ktile
  int ktiles = K >> 5;
  int kt = rest % ktiles;
  int nt = rest / ktiles;
  int n = nt * 16 + (lane & 15);
  int k = kt * 32 + (lane >> 4) * 8 + j;
  dst[idx] = (_Float16)src[n * K + k];
}

// LDS swizzle: phys(row, colbyte) = row*STRIDE + (colbyte ^ ((row&7)<<4))

__global__ __launch_bounds__(512, 2)
void fused_linkpred(const float* __restrict__ z, const int* __restrict__ ei, int E,
                    const float* __restrict__ b1, const float* __restrict__ b2,
                    const float* __restrict__ b3, const float* __restrict__ W4,
                    const float* __restrict__ b4,
                    const _Float16* __restrict__ wbuf, float* __restrict__ out) {
  extern __shared__ char smem[];            // [0,131072): X0/X1 [128][512] f16 (aliased), X2 [128][256] f16
  float* scratch = (float*)(smem + 131072); // [128][4] floats

  const int tid  = threadIdx.x;
  const int wid  = tid >> 6;
  const int lane = tid & 63;
  const int l15  = lane & 15;
  const int lhi  = lane >> 4;
  const int base = blockIdx.x * 128;
  const int wr   = wid >> 2;   // 0..1 (row half for layers 2/3)
  const int wc   = wid & 3;    // 0..3 (col quarter for layers 2/3)

  const _Float16* w1 = wbuf;
  const _Float16* w2 = wbuf + W1E;
  const _Float16* w3 = wbuf + W1E + W2E;

  // preload biases / w4 (per-lane, hides latency under gather)
  float bias1[4], bias2[4], bias3[4], w4v[4];
  #pragma unroll
  for (int nf = 0; nf < 4; ++nf) {
    bias1[nf] = b1[wid*64 + nf*16 + l15];
    bias2[nf] = b2[wc*64  + nf*16 + l15];
    bias3[nf] = b3[wc*64  + nf*16 + l15];
    w4v[nf]   = W4[wc*64  + nf*16 + l15];
  }

  // ---------- gather X0 = [z[row] | z[col]] as f16, swizzled, row stride 1024B
  for (int it = wid; it < 256; it += 8) {   // 256 tasks = 128 edges x 2 halves
    int e = it >> 1, half = it & 1;
    int ge = base + e; if (ge >= E) ge = E - 1;       // clamp tail (output guarded)
    int src = ei[half ? (E + ge) : ge];
    float4 v = *(const float4*)(z + src * 256 + lane * 4);  // coalesced 1KB/wave
    f16x4 h;
    h[0] = (_Float16)v.x; h[1] = (_Float16)v.y; h[2] = (_Float16)v.z; h[3] = (_Float16)v.w;
    int off = e * 1024 + ((half * 512 + lane * 8) ^ ((e & 7) << 4));
    *(f16x4*)(smem + off) = h;
  }
  __syncthreads();

  // ---------- layer1: X1 = relu(X0 @ W1^T + b1)   wave = 128 rows x 64 cols
  f32x4 acc1[8][4];
  #pragma unroll
  for (int m = 0; m < 8; ++m)
    #pragma unroll
    for (int nf = 0; nf < 4; ++nf) acc1[m][nf] = (f32x4){0.f, 0.f, 0.f, 0.f};

  for (int kt = 0; kt < 16; ++kt) {
    f16x8 bb[4];
    #pragma unroll
    for (int nf = 0; nf < 4; ++nf)
      bb[nf] = *(const f16x8*)(w1 + (((wid*4 + nf)*16 + kt)*64 + lane) * 8);
    #pragma unroll
    for (int m = 0; m < 8; ++m) {
      int row = m * 16 + l15;
      f16x8 a = *(const f16x8*)(smem + row * 1024 + ((kt*64 + lhi*16) ^ ((row & 7) << 4)));
      #pragma unroll
      for (int nf = 0; nf < 4; ++nf)
        acc1[m][nf] = __builtin_amdgcn_mfma_f32_16x16x32_f16(a, bb[nf], acc1[m][nf], 0, 0, 0);
    }
  }
  __syncthreads();   // all X0 reads done; X1 overwrites same region
  #pragma unroll
  for (int m = 0; m < 8; ++m)
    #pragma unroll
    for (int nf = 0; nf < 4; ++nf) {
      int col = wid*64 + nf*16 + l15;
      #pragma unroll
      for (int r = 0; r < 4; ++r) {
        int row = m*16 + lhi*4 + r;                 // C/D: row=(lane>>4)*4+reg, col=lane&15
        float v = acc1[m][nf][r] + bias1[nf];
        v = fmaxf(v, 0.f);
        *(_Float16*)(smem + row * 1024 + ((col * 2) ^ ((row & 7) << 4))) = (_Float16)v;
      }
    }
  __syncthreads();

  // ---------- layer2: X2 = relu(X1 @ W2^T + b2)   wave = 64 rows x 64 cols
  f32x4 acc2[4][4];
  #pragma unroll
  for (int m = 0; m < 4; ++m)
    #pragma unroll
    for (int nf = 0; nf < 4; ++nf) acc2[m][nf] = (f32x4){0.f, 0.f, 0.f, 0.f};

  for (int kt = 0; kt < 16; ++kt) {
    f16x8 bb[4];
    #pragma unroll
    for (int nf = 0; nf < 4; ++nf)
      bb[nf] = *(const f16x8*)(w2 + (((wc*4 + nf)*16 + kt)*64 + lane) * 8);
    #pragma unroll
    for (int m = 0; m < 4; ++m) {
      int row = wr*64 + m*16 + l15;
      f16x8 a = *(const f16x8*)(smem + row * 1024 + ((kt*64 + lhi*16) ^ ((row & 7) << 4)));
      #pragma unroll
      for (int nf = 0; nf < 4; ++nf)
        acc2[m][nf] = __builtin_amdgcn_mfma_f32_16x16x32_f16(a, bb[nf], acc2[m][nf], 0, 0, 0);
    }
  }
  __syncthreads();   // X1 reads done; X2 [128][256] stride 512B overwrites
  #pragma unroll
  for (int m = 0; m < 4; ++m)
    #pragma unroll
    for (int nf = 0; nf < 4; ++nf) {
      int col = wc*64 + nf*16 + l15;
      #pragma unroll
      for (int r = 0; r < 4; ++r) {
        int row = wr*64 + m*16 + lhi*4 + r;
        float v = acc2[m][nf][r] + bias2[nf];
        v = fmaxf(v, 0.f);
        *(_Float16*)(smem + row * 512 + ((col * 2) ^ ((row & 7) << 4))) = (_Float16)v;
      }
    }
  __syncthreads();

  // ---------- layer3: X3 = relu(X2 @ W3^T + b3)   wave = 64 rows x 64 cols
  f32x4 acc3[4][4];
  #pragma unroll
  for (int m = 0; m < 4; ++m)
    #pragma unroll
    for (int nf = 0; nf < 4; ++nf) acc3[m][nf] = (f32x4){0.f, 0.f, 0.f, 0.f};

  for (int kt = 0; kt < 8; ++kt) {
    f16x8 bb[4];
    #pragma unroll
    for (int nf = 0; nf < 4; ++nf)
      bb[nf] = *(const f16x8*)(w3 + (((wc*4 + nf)*8 + kt)*64 + lane) * 8);
    #pragma unroll
    for (int m = 0; m < 4; ++m) {
      int row = wr*64 + m*16 + l15;
      f16x8 a = *(const f16x8*)(smem + row * 512 + ((kt*64 + lhi*16) ^ ((row & 7) << 4)));
      #pragma unroll
      for (int nf = 0; nf < 4; ++nf)
        acc3[m][nf] = __builtin_amdgcn_mfma_f32_16x16x32_f16(a, bb[nf], acc3[m][nf], 0, 0, 0);
    }
  }

  // ---------- layer4: out = sigmoid(X3 . w4 + b4), reduced from fragments
  #pragma unroll
  for (int m = 0; m < 4; ++m)
    #pragma unroll
    for (int r = 0; r < 4; ++r) {
      float p = 0.f;
      #pragma unroll
      for (int nf = 0; nf < 4; ++nf) {
        float v = acc3[m][nf][r] + bias3[nf];
        v = fmaxf(v, 0.f);
        p += v * w4v[nf];
      }
      p += __shfl_xor(p, 1);
      p += __shfl_xor(p, 2);
      p += __shfl_xor(p, 4);
      p += __shfl_xor(p, 8);   // 16-lane group sum (cols of this wave)
      if (l15 == 0) scratch[(wr*64 + m*16 + lhi*4 + r) * 4 + wc] = p;
    }
  __syncthreads();

  if (tid < 128) {
    int ge = base + tid;
    if (ge < E) {
      float s = b4[0] + scratch[tid*4+0] + scratch[tid*4+1] + scratch[tid*4+2] + scratch[tid*4+3];
      out[ge] = 1.f / (1.f + expf(-s));
    }
  }
}

extern "C" void kernel_launch(void* const* d_in, const int* in_sizes, int n_in,
                              void* d_out, int out_size, void* d_ws, size_t ws_size,
                              hipStream_t stream) {
  const float* z  = (const float*)d_in[0];
  const int*   ei = (const int*)d_in[1];
  const float* W1 = (const float*)d_in[2];
  const float* b1 = (const float*)d_in[3];
  const float* W2 = (const float*)d_in[4];
  const float* b2 = (const float*)d_in[5];
  const float* W3 = (const float*)d_in[6];
  const float* b3 = (const float*)d_in[7];
  const float* W4 = (const float*)d_in[8];
  const float* b4 = (const float*)d_in[9];
  float* out = (float*)d_out;
  const int E = in_sizes[1] / 2;
  _Float16* wbuf = (_Float16*)d_ws;   // needs 917504 B

  repack_w<<<(WTOT + 255) / 256, 256, 0, stream>>>(W1, W2, W3, wbuf);

  int nblk = (E + 127) / 128;
  fused_linkpred<<<nblk, 512, 131072 + 2048, stream>>>(z, ei, E, b1, b2, b3, W4, b4, wbuf, out);
}

// Round 2
// 680.349 us; speedup vs baseline: 1.0816x; 1.0816x over previous
//
#include <hip/hip_runtime.h>
#include <math.h>

// LinkPredictor fused MLP for MI355X (gfx950) — round 2.
// Block = 64 edges (X-buffer 64KB -> 2 blocks/CU, 4 waves/SIMD).
// MFMA operands swapped: D[neuron][edge] = mfma(Wfrag, Xfrag) so writeback is
// packed ds_write_b64 (4 consecutive neurons per lane). Biases in LDS table,
// folded into accumulator init.

typedef _Float16 f16x8 __attribute__((ext_vector_type(8)));
typedef _Float16 f16x4 __attribute__((ext_vector_type(4)));
typedef float    f32x4 __attribute__((ext_vector_type(4)));

#define W1E (512*512)
#define W2E (256*512)
#define W3E (256*256)
#define WTOT (W1E+W2E+W3E)

// Repack W[N][K] fp32 -> f16 fragment stream:
// dst[((ntile*(K/32)+ktile)*64 + lane)*8 + j] = W[ntile*16+(lane&15)][ktile*32+(lane>>4)*8+j]
// (serves as the MFMA *A* fragment: A[row=neuron=lane&15][k=(lane>>4)*8+j])
__global__ void repack_w(const float* __restrict__ W1, const float* __restrict__ W2,
                         const float* __restrict__ W3, _Float16* __restrict__ wout) {
  int t = blockIdx.x * 256 + threadIdx.x;
  if (t >= WTOT) return;
  const float* src; _Float16* dst; int K, idx;
  if (t < W1E)            { src = W1; K = 512; idx = t;             dst = wout; }
  else if (t < W1E + W2E) { src = W2; K = 512; idx = t - W1E;       dst = wout + W1E; }
  else                    { src = W3; K = 256; idx = t - (W1E+W2E); dst = wout + W1E + W2E; }
  int j    = idx & 7;
  int lane = (idx >> 3) & 63;
  int rest = idx >> 9;              // = ntile*(K/32) + ktile
  int ktiles = K >> 5;
  int kt = rest % ktiles;
  int nt = rest / ktiles;
  int n = nt * 16 + (lane & 15);
  int k = kt * 32 + (lane >> 4) * 8 + j;
  dst[idx] = (_Float16)src[n * K + k];
}

// LDS map (per block, dynamic):
//   [0, 65536)        X buffer: X0/X1 [64][512] f16 stride 1024B (aliased), X2 [64][256] stride 512B
//   [65536, 67584)    scratch: float [64 edges][8 waves]
//   [67584, 72708)    bias table floats: b1[512] b2[256] b3[256] w4[256] b4[1]
#define SCR_OFF  65536
#define BIAS_OFF 67584
#define LDS_BYTES 72832

__global__ __launch_bounds__(512, 4)
void fused_linkpred(const float* __restrict__ z, const int* __restrict__ ei, int E,
                    const float* __restrict__ b1, const float* __restrict__ b2,
                    const float* __restrict__ b3, const float* __restrict__ W4,
                    const float* __restrict__ b4,
                    const _Float16* __restrict__ wbuf, float* __restrict__ out) {
  extern __shared__ char smem[];
  float* scr = (float*)(smem + SCR_OFF);
  float* bls = (float*)(smem + BIAS_OFF);

  const int tid  = threadIdx.x;
  const int wid  = tid >> 6;
  const int lane = tid & 63;
  const int l15  = lane & 15;
  const int lhi  = lane >> 4;
  const int base = blockIdx.x * 64;

  // ---- bias table -> LDS (covered by the gather barrier)
  for (int i = tid; i < 1281; i += 512) {
    float v;
    if (i < 512)       v = b1[i];
    else if (i < 768)  v = b2[i - 512];
    else if (i < 1024) v = b3[i - 768];
    else if (i < 1280) v = W4[i - 1024];
    else               v = b4[0];
    bls[i] = v;
  }

  // ---- gather X0 = [z[row] | z[col]] as f16, swizzled (byte ^ ((edge&7)<<4))
  for (int it = wid; it < 128; it += 8) {   // 64 edges x 2 halves
    int e = it >> 1, half = it & 1;
    int ge = base + e; if (ge >= E) ge = E - 1;
    int src = ei[half ? (E + ge) : ge];
    float4 v = *(const float4*)(z + (size_t)src * 256 + lane * 4);
    f16x4 h;
    h[0] = (_Float16)v.x; h[1] = (_Float16)v.y; h[2] = (_Float16)v.z; h[3] = (_Float16)v.w;
    *(f16x4*)(smem + e * 1024 + ((half * 512 + lane * 8) ^ ((e & 7) << 4))) = h;
  }
  __syncthreads();

  const _Float16* w1 = wbuf;
  const _Float16* w2 = wbuf + W1E;
  const _Float16* w3 = wbuf + W1E + W2E;

  // ---------- layer1: X1^T tiles = W1 @ X0^T; wave owns neurons wid*64..+63, all 64 edges
  f32x4 acc1[4][4];
  #pragma unroll
  for (int nt = 0; nt < 4; ++nt) {
    f32x4 bv = *(const f32x4*)(bls + wid*64 + nt*16 + lhi*4);
    #pragma unroll
    for (int et = 0; et < 4; ++et) acc1[nt][et] = bv;
  }
  for (int kt = 0; kt < 16; ++kt) {
    f16x8 wf[4], xf[4];
    #pragma unroll
    for (int nt = 0; nt < 4; ++nt)
      wf[nt] = *(const f16x8*)(w1 + (((wid*4 + nt)*16 + kt)*64 + lane) * 8);
    #pragma unroll
    for (int et = 0; et < 4; ++et) {
      int e = et*16 + l15;
      xf[et] = *(const f16x8*)(smem + e * 1024 + ((kt*64 + lhi*16) ^ ((e & 7) << 4)));
    }
    #pragma unroll
    for (int nt = 0; nt < 4; ++nt)
      #pragma unroll
      for (int et = 0; et < 4; ++et)
        acc1[nt][et] = __builtin_amdgcn_mfma_f32_16x16x32_f16(wf[nt], xf[et], acc1[nt][et], 0, 0, 0);
  }
  __syncthreads();   // all X0 reads done before X1 overwrites
  #pragma unroll
  for (int nt = 0; nt < 4; ++nt)
    #pragma unroll
    for (int et = 0; et < 4; ++et) {
      int e = et*16 + l15;
      int ncb = (wid*64 + nt*16 + lhi*4) * 2;   // neuron col byte (8B aligned)
      f16x4 h;
      #pragma unroll
      for (int r = 0; r < 4; ++r) h[r] = (_Float16)fmaxf(acc1[nt][et][r], 0.f);
      *(f16x4*)(smem + e * 1024 + (ncb ^ ((e & 7) << 4))) = h;
    }
  __syncthreads();

  // ---------- layer2: wave owns neurons wid*32..+31, all 64 edges (K=512)
  f32x4 acc2[2][4];
  #pragma unroll
  for (int nt = 0; nt < 2; ++nt) {
    f32x4 bv = *(const f32x4*)(bls + 512 + wid*32 + nt*16 + lhi*4);
    #pragma unroll
    for (int et = 0; et < 4; ++et) acc2[nt][et] = bv;
  }
  for (int kt = 0; kt < 16; ++kt) {
    f16x8 wf[2], xf[4];
    #pragma unroll
    for (int nt = 0; nt < 2; ++nt)
      wf[nt] = *(const f16x8*)(w2 + (((wid*2 + nt)*16 + kt)*64 + lane) * 8);
    #pragma unroll
    for (int et = 0; et < 4; ++et) {
      int e = et*16 + l15;
      xf[et] = *(const f16x8*)(smem + e * 1024 + ((kt*64 + lhi*16) ^ ((e & 7) << 4)));
    }
    #pragma unroll
    for (int nt = 0; nt < 2; ++nt)
      #pragma unroll
      for (int et = 0; et < 4; ++et)
        acc2[nt][et] = __builtin_amdgcn_mfma_f32_16x16x32_f16(wf[nt], xf[et], acc2[nt][et], 0, 0, 0);
  }
  __syncthreads();   // X1 reads done; X2 [64][256] stride 512B overwrites
  #pragma unroll
  for (int nt = 0; nt < 2; ++nt)
    #pragma unroll
    for (int et = 0; et < 4; ++et) {
      int e = et*16 + l15;
      int ncb = (wid*32 + nt*16 + lhi*4) * 2;
      f16x4 h;
      #pragma unroll
      for (int r = 0; r < 4; ++r) h[r] = (_Float16)fmaxf(acc2[nt][et][r], 0.f);
      *(f16x4*)(smem + e * 512 + (ncb ^ ((e & 7) << 4))) = h;
    }
  __syncthreads();

  // ---------- layer3: wave owns neurons wid*32..+31, all 64 edges (K=256)
  f32x4 acc3[2][4];
  #pragma unroll
  for (int nt = 0; nt < 2; ++nt) {
    f32x4 bv = *(const f32x4*)(bls + 768 + wid*32 + nt*16 + lhi*4);
    #pragma unroll
    for (int et = 0; et < 4; ++et) acc3[nt][et] = bv;
  }
  for (int kt = 0; kt < 8; ++kt) {
    f16x8 wf[2], xf[4];
    #pragma unroll
    for (int nt = 0; nt < 2; ++nt)
      wf[nt] = *(const f16x8*)(w3 + (((wid*2 + nt)*8 + kt)*64 + lane) * 8);
    #pragma unroll
    for (int et = 0; et < 4; ++et) {
      int e = et*16 + l15;
      xf[et] = *(const f16x8*)(smem + e * 512 + ((kt*64 + lhi*16) ^ ((e & 7) << 4)));
    }
    #pragma unroll
    for (int nt = 0; nt < 2; ++nt)
      #pragma unroll
      for (int et = 0; et < 4; ++et)
        acc3[nt][et] = __builtin_amdgcn_mfma_f32_16x16x32_f16(wf[nt], xf[et], acc3[nt][et], 0, 0, 0);
  }

  // ---------- layer4: out = sigmoid(sum_n relu(X3) * w4 + b4)
  f32x4 w4v[2];
  #pragma unroll
  for (int nt = 0; nt < 2; ++nt)
    w4v[nt] = *(const f32x4*)(bls + 1024 + wid*32 + nt*16 + lhi*4);
  float bias4 = bls[1280];

  #pragma unroll
  for (int et = 0; et < 4; ++et) {
    float p = 0.f;
    #pragma unroll
    for (int nt = 0; nt < 2; ++nt)
      #pragma unroll
      for (int r = 0; r < 4; ++r)
        p += fmaxf(acc3[nt][et][r], 0.f) * w4v[nt][r];
    p += __shfl_xor(p, 16);
    p += __shfl_xor(p, 32);          // sum over the 4 lhi groups (wave's 32 neurons)
    if (lane < 16) scr[(et*16 + l15) * 8 + wid] = p;
  }
  __syncthreads();

  if (tid < 64) {
    int ge = base + tid;
    if (ge < E) {
      float s = bias4;
      #pragma unroll
      for (int w = 0; w < 8; ++w) s += scr[tid*8 + w];
      out[ge] = 1.f / (1.f + expf(-s));
    }
  }
}

extern "C" void kernel_launch(void* const* d_in, const int* in_sizes, int n_in,
                              void* d_out, int out_size, void* d_ws, size_t ws_size,
                              hipStream_t stream) {
  const float* z  = (const float*)d_in[0];
  const int*   ei = (const int*)d_in[1];
  const float* W1 = (const float*)d_in[2];
  const float* b1 = (const float*)d_in[3];
  const float* W2 = (const float*)d_in[4];
  const float* b2 = (const float*)d_in[5];
  const float* W3 = (const float*)d_in[6];
  const float* b3 = (const float*)d_in[7];
  const float* W4 = (const float*)d_in[8];
  const float* b4 = (const float*)d_in[9];
  float* out = (float*)d_out;
  const int E = in_sizes[1] / 2;
  _Float16* wbuf = (_Float16*)d_ws;   // needs 917504 B

  repack_w<<<(WTOT + 255) / 256, 256, 0, stream>>>(W1, W2, W3, wbuf);

  int nblk = (E + 63) / 64;
  fused_linkpred<<<nblk, 512, LDS_BYTES, stream>>>(z, ei, E, b1, b2, b3, W4, b4, wbuf, out);
}

// Round 3
// 450.330 us; speedup vs baseline: 1.6341x; 1.5108x over previous
//
#include <hip/hip_runtime.h>
#include <math.h>

// LinkPredictor fused MLP for MI355X (gfx950) — round 3.
// Key change: layer 1 is algebraically split per-node:
//   X1[e] = relu(W1a z[row] + b1 + W1b z[col])
// Precompute Ha[n] = W1a z[n] + b1, Hb[n] = W1b z[n] for all nodes (52 GF
// instead of 262 GF at edge level), store f16 [N][1024] in d_ws. Edge kernel
// gathers Ha[row], Hb[col], does packed f16 add+relu -> X1 in LDS, then
// layers 2/3/4 via MFMA. Removes the layer-1 register pressure that caused
// round-2's scratch spill (470 MB WRITE_SIZE).

typedef _Float16 f16x8 __attribute__((ext_vector_type(8)));
typedef _Float16 f16x4 __attribute__((ext_vector_type(4)));
typedef float    f32x4 __attribute__((ext_vector_type(4)));

#define W1E (512*512)
#define W2E (256*512)
#define W3E (256*256)
#define WTOT (W1E+W2E+W3E)
#define H_OFF 1048576   // byte offset of H in d_ws

// Repack W[N][K] fp32 -> f16 MFMA A-fragment stream:
// dst[((ntile*(K/32)+ktile)*64 + lane)*8 + j] = W[ntile*16+(lane&15)][ktile*32+(lane>>4)*8+j]
__global__ void repack_w(const float* __restrict__ W1, const float* __restrict__ W2,
                         const float* __restrict__ W3, _Float16* __restrict__ wout) {
  int t = blockIdx.x * 256 + threadIdx.x;
  if (t >= WTOT) return;
  const float* src; _Float16* dst; int K, idx;
  if (t < W1E)            { src = W1; K = 512; idx = t;             dst = wout; }
  else if (t < W1E + W2E) { src = W2; K = 512; idx = t - W1E;       dst = wout + W1E; }
  else                    { src = W3; K = 256; idx = t - (W1E+W2E); dst = wout + W1E + W2E; }
  int j    = idx & 7;
  int lane = (idx >> 3) & 63;
  int rest = idx >> 9;
  int ktiles = K >> 5;
  int kt = rest % ktiles;
  int nt = rest / ktiles;
  int n = nt * 16 + (lane & 15);
  int k = kt * 32 + (lane >> 4) * 8 + j;
  dst[idx] = (_Float16)src[n * K + k];
}

// ---------------- precompute H: Ha[n] = W1[:, :256] z[n] + b1 ; Hb[n] = W1[:,256:] z[n]
// grid = (ceil(N/64), 2). blockIdx.y = 0 -> Ha (ktiles 0..7 of W1, +b1), 1 -> Hb (ktiles 8..15).
// H layout: f16 H[n][1024], [0,512) = Ha, [512,1024) = Hb.
__global__ __launch_bounds__(512, 2)
void precompute_h(const float* __restrict__ z, int N, const float* __restrict__ b1,
                  const _Float16* __restrict__ w1, _Float16* __restrict__ H) {
  __shared__ char smem[32768];     // z block [64][256] f16, stride 512B, swizzled
  const int tid  = threadIdx.x;
  const int wid  = tid >> 6;
  const int lane = tid & 63;
  const int l15  = lane & 15;
  const int lhi  = lane >> 4;
  const int nbase = blockIdx.x * 64;
  const int cb    = blockIdx.y;

  for (int r = wid; r < 64; r += 8) {
    int n = nbase + r; if (n >= N) n = N - 1;
    float4 v = *(const float4*)(z + (size_t)n * 256 + lane * 4);
    f16x4 h;
    h[0] = (_Float16)v.x; h[1] = (_Float16)v.y; h[2] = (_Float16)v.z; h[3] = (_Float16)v.w;
    *(f16x4*)(smem + r * 512 + ((lane * 8) ^ ((r & 7) << 4))) = h;
  }
  __syncthreads();

  f32x4 acc[4][4];
  #pragma unroll
  for (int nt = 0; nt < 4; ++nt) {
    f32x4 bv = (f32x4){0.f, 0.f, 0.f, 0.f};
    if (cb == 0) bv = *(const f32x4*)(b1 + wid*64 + nt*16 + lhi*4);
    #pragma unroll
    for (int et = 0; et < 4; ++et) acc[nt][et] = bv;
  }

  for (int kt = 0; kt < 8; ++kt) {
    int ktw = kt + cb * 8;
    f16x8 wf[4], xf[4];
    #pragma unroll
    for (int nt = 0; nt < 4; ++nt)
      wf[nt] = *(const f16x8*)(w1 + (((wid*4 + nt)*16 + ktw)*64 + lane) * 8);
    #pragma unroll
    for (int et = 0; et < 4; ++et) {
      int r = et*16 + l15;
      xf[et] = *(const f16x8*)(smem + r * 512 + ((kt*64 + lhi*16) ^ ((r & 7) << 4)));
    }
    #pragma unroll
    for (int nt = 0; nt < 4; ++nt)
      #pragma unroll
      for (int et = 0; et < 4; ++et)
        acc[nt][et] = __builtin_amdgcn_mfma_f32_16x16x32_f16(wf[nt], xf[et], acc[nt][et], 0, 0, 0);
  }

  #pragma unroll
  for (int nt = 0; nt < 4; ++nt)
    #pragma unroll
    for (int et = 0; et < 4; ++et) {
      int n = nbase + et*16 + l15;
      if (n < N) {
        f16x4 h;
        #pragma unroll
        for (int r = 0; r < 4; ++r) h[r] = (_Float16)acc[nt][et][r];
        *(f16x4*)(H + (size_t)n * 1024 + cb*512 + wid*64 + nt*16 + lhi*4) = h;
      }
    }
}

// ---------------- fused edge kernel: X1 = relu(Ha[row]+Hb[col]) -> layers 2/3/4
// LDS: [0,65536) X1 [64][512] f16 stride 1024B (X2 [64][256] stride 512B aliased)
//      [65536,67584) scratch [64][8] f32
//      [67584,+3076) bias floats: b2[256] b3[256] w4[256] b4[1]
#define SCR_OFF  65536
#define BIAS_OFF 67584
#define LDS2_BYTES (BIAS_OFF + 3080)

__global__ __launch_bounds__(512, 4)
void fused_edges(const int* __restrict__ ei, int E, const _Float16* __restrict__ H,
                 const float* __restrict__ b2, const float* __restrict__ b3,
                 const float* __restrict__ W4, const float* __restrict__ b4,
                 const _Float16* __restrict__ w2, const _Float16* __restrict__ w3,
                 float* __restrict__ out) {
  extern __shared__ char smem[];
  float* scr = (float*)(smem + SCR_OFF);
  float* bls = (float*)(smem + BIAS_OFF);

  const int tid  = threadIdx.x;
  const int wid  = tid >> 6;
  const int lane = tid & 63;
  const int l15  = lane & 15;
  const int lhi  = lane >> 4;
  const int base = blockIdx.x * 64;

  for (int i = tid; i < 769; i += 512) {
    float v;
    if (i < 256)      v = b2[i];
    else if (i < 512) v = b3[i - 256];
    else if (i < 768) v = W4[i - 512];
    else              v = b4[0];
    bls[i] = v;
  }

  // ---- build X1: wave handles edges wid, wid+8, ... (full 1KB row per edge)
  #pragma unroll 4
  for (int e8 = 0; e8 < 8; ++e8) {
    int e = e8 * 8 + wid;
    int ge = base + e; if (ge >= E) ge = E - 1;
    int nr = ei[ge];
    int nc = ei[E + ge];
    f16x8 ha = *(const f16x8*)(H + (size_t)nr * 1024 + lane * 8);
    f16x8 hb = *(const f16x8*)(H + (size_t)nc * 1024 + 512 + lane * 8);
    f16x8 s = ha + hb;
    #pragma unroll
    for (int j = 0; j < 8; ++j) s[j] = (s[j] > (_Float16)0) ? s[j] : (_Float16)0;
    *(f16x8*)(smem + e * 1024 + ((lane * 16) ^ ((e & 7) << 4))) = s;
  }
  __syncthreads();

  // ---------- layer2: wave owns neurons wid*32..+31, all 64 edges (K=512)
  f32x4 acc2[2][4];
  #pragma unroll
  for (int nt = 0; nt < 2; ++nt) {
    f32x4 bv = *(const f32x4*)(bls + wid*32 + nt*16 + lhi*4);
    #pragma unroll
    for (int et = 0; et < 4; ++et) acc2[nt][et] = bv;
  }
  for (int kt = 0; kt < 16; ++kt) {
    f16x8 wf[2], xf[4];
    #pragma unroll
    for (int nt = 0; nt < 2; ++nt)
      wf[nt] = *(const f16x8*)(w2 + (((wid*2 + nt)*16 + kt)*64 + lane) * 8);
    #pragma unroll
    for (int et = 0; et < 4; ++et) {
      int e = et*16 + l15;
      xf[et] = *(const f16x8*)(smem + e * 1024 + ((kt*64 + lhi*16) ^ ((e & 7) << 4)));
    }
    #pragma unroll
    for (int nt = 0; nt < 2; ++nt)
      #pragma unroll
      for (int et = 0; et < 4; ++et)
        acc2[nt][et] = __builtin_amdgcn_mfma_f32_16x16x32_f16(wf[nt], xf[et], acc2[nt][et], 0, 0, 0);
  }
  __syncthreads();   // X1 reads done; X2 [64][256] stride 512B overwrites
  #pragma unroll
  for (int nt = 0; nt < 2; ++nt)
    #pragma unroll
    for (int et = 0; et < 4; ++et) {
      int e = et*16 + l15;
      int ncb = (wid*32 + nt*16 + lhi*4) * 2;
      f16x4 h;
      #pragma unroll
      for (int r = 0; r < 4; ++r) h[r] = (_Float16)fmaxf(acc2[nt][et][r], 0.f);
      *(f16x4*)(smem + e * 512 + (ncb ^ ((e & 7) << 4))) = h;
    }
  __syncthreads();

  // ---------- layer3: wave owns neurons wid*32..+31, all 64 edges (K=256)
  f32x4 acc3[2][4];
  #pragma unroll
  for (int nt = 0; nt < 2; ++nt) {
    f32x4 bv = *(const f32x4*)(bls + 256 + wid*32 + nt*16 + lhi*4);
    #pragma unroll
    for (int et = 0; et < 4; ++et) acc3[nt][et] = bv;
  }
  for (int kt = 0; kt < 8; ++kt) {
    f16x8 wf[2], xf[4];
    #pragma unroll
    for (int nt = 0; nt < 2; ++nt)
      wf[nt] = *(const f16x8*)(w3 + (((wid*2 + nt)*8 + kt)*64 + lane) * 8);
    #pragma unroll
    for (int et = 0; et < 4; ++et) {
      int e = et*16 + l15;
      xf[et] = *(const f16x8*)(smem + e * 512 + ((kt*64 + lhi*16) ^ ((e & 7) << 4)));
    }
    #pragma unroll
    for (int nt = 0; nt < 2; ++nt)
      #pragma unroll
      for (int et = 0; et < 4; ++et)
        acc3[nt][et] = __builtin_amdgcn_mfma_f32_16x16x32_f16(wf[nt], xf[et], acc3[nt][et], 0, 0, 0);
  }

  // ---------- layer4: out = sigmoid(sum_n relu(X3)*w4 + b4)
  f32x4 w4v[2];
  #pragma unroll
  for (int nt = 0; nt < 2; ++nt)
    w4v[nt] = *(const f32x4*)(bls + 512 + wid*32 + nt*16 + lhi*4);
  float bias4 = bls[768];

  #pragma unroll
  for (int et = 0; et < 4; ++et) {
    float p = 0.f;
    #pragma unroll
    for (int nt = 0; nt < 2; ++nt)
      #pragma unroll
      for (int r = 0; r < 4; ++r)
        p += fmaxf(acc3[nt][et][r], 0.f) * w4v[nt][r];
    p += __shfl_xor(p, 16);
    p += __shfl_xor(p, 32);
    if (lane < 16) scr[(et*16 + l15) * 8 + wid] = p;
  }
  __syncthreads();

  if (tid < 64) {
    int ge = base + tid;
    if (ge < E) {
      float s = bias4;
      #pragma unroll
      for (int w = 0; w < 8; ++w) s += scr[tid*8 + w];
      out[ge] = 1.f / (1.f + expf(-s));
    }
  }
}

// ---------------- fallback (ws too small): round-2 style fully-fused kernel
#define FSCR_OFF  65536
#define FBIAS_OFF 67584
#define FLDS_BYTES 72832

__global__ __launch_bounds__(512, 2)
void fused_fallback(const float* __restrict__ z, const int* __restrict__ ei, int E,
                    const float* __restrict__ b1, const float* __restrict__ b2,
                    const float* __restrict__ b3, const float* __restrict__ W4,
                    const float* __restrict__ b4,
                    const _Float16* __restrict__ wbuf, float* __restrict__ out) {
  extern __shared__ char smem[];
  float* scr = (float*)(smem + FSCR_OFF);
  float* bls = (float*)(smem + FBIAS_OFF);

  const int tid  = threadIdx.x;
  const int wid  = tid >> 6;
  const int lane = tid & 63;
  const int l15  = lane & 15;
  const int lhi  = lane >> 4;
  const int base = blockIdx.x * 64;

  for (int i = tid; i < 1281; i += 512) {
    float v;
    if (i < 512)       v = b1[i];
    else if (i < 768)  v = b2[i - 512];
    else if (i < 1024) v = b3[i - 768];
    else if (i < 1280) v = W4[i - 1024];
    else               v = b4[0];
    bls[i] = v;
  }

  for (int it = wid; it < 128; it += 8) {
    int e = it >> 1, half = it & 1;
    int ge = base + e; if (ge >= E) ge = E - 1;
    int src = ei[half ? (E + ge) : ge];
    float4 v = *(const float4*)(z + (size_t)src * 256 + lane * 4);
    f16x4 h;
    h[0] = (_Float16)v.x; h[1] = (_Float16)v.y; h[2] = (_Float16)v.z; h[3] = (_Float16)v.w;
    *(f16x4*)(smem + e * 1024 + ((half * 512 + lane * 8) ^ ((e & 7) << 4))) = h;
  }
  __syncthreads();

  const _Float16* w1 = wbuf;
  const _Float16* w2 = wbuf + W1E;
  const _Float16* w3 = wbuf + W1E + W2E;

  f32x4 acc1[4][4];
  #pragma unroll
  for (int nt = 0; nt < 4; ++nt) {
    f32x4 bv = *(const f32x4*)(bls + wid*64 + nt*16 + lhi*4);
    #pragma unroll
    for (int et = 0; et < 4; ++et) acc1[nt][et] = bv;
  }
  for (int kt = 0; kt < 16; ++kt) {
    f16x8 wf[4], xf[4];
    #pragma unroll
    for (int nt = 0; nt < 4; ++nt)
      wf[nt] = *(const f16x8*)(w1 + (((wid*4 + nt)*16 + kt)*64 + lane) * 8);
    #pragma unroll
    for (int et = 0; et < 4; ++et) {
      int e = et*16 + l15;
      xf[et] = *(const f16x8*)(smem + e * 1024 + ((kt*64 + lhi*16) ^ ((e & 7) << 4)));
    }
    #pragma unroll
    for (int nt = 0; nt < 4; ++nt)
      #pragma unroll
      for (int et = 0; et < 4; ++et)
        acc1[nt][et] = __builtin_amdgcn_mfma_f32_16x16x32_f16(wf[nt], xf[et], acc1[nt][et], 0, 0, 0);
  }
  __syncthreads();
  #pragma unroll
  for (int nt = 0; nt < 4; ++nt)
    #pragma unroll
    for (int et = 0; et < 4; ++et) {
      int e = et*16 + l15;
      int ncb = (wid*64 + nt*16 + lhi*4) * 2;
      f16x4 h;
      #pragma unroll
      for (int r = 0; r < 4; ++r) h[r] = (_Float16)fmaxf(acc1[nt][et][r], 0.f);
      *(f16x4*)(smem + e * 1024 + (ncb ^ ((e & 7) << 4))) = h;
    }
  __syncthreads();

  f32x4 acc2[2][4];
  #pragma unroll
  for (int nt = 0; nt < 2; ++nt) {
    f32x4 bv = *(const f32x4*)(bls + 512 + wid*32 + nt*16 + lhi*4);
    #pragma unroll
    for (int et = 0; et < 4; ++et) acc2[nt][et] = bv;
  }
  for (int kt = 0; kt < 16; ++kt) {
    f16x8 wf[2], xf[4];
    #pragma unroll
    for (int nt = 0; nt < 2; ++nt)
      wf[nt] = *(const f16x8*)(w2 + (((wid*2 + nt)*16 + kt)*64 + lane) * 8);
    #pragma unroll
    for (int et = 0; et < 4; ++et) {
      int e = et*16 + l15;
      xf[et] = *(const f16x8*)(smem + e * 1024 + ((kt*64 + lhi*16) ^ ((e & 7) << 4)));
    }
    #pragma unroll
    for (int nt = 0; nt < 2; ++nt)
      #pragma unroll
      for (int et = 0; et < 4; ++et)
        acc2[nt][et] = __builtin_amdgcn_mfma_f32_16x16x32_f16(wf[nt], xf[et], acc2[nt][et], 0, 0, 0);
  }
  __syncthreads();
  #pragma unroll
  for (int nt = 0; nt < 2; ++nt)
    #pragma unroll
    for (int et = 0; et < 4; ++et) {
      int e = et*16 + l15;
      int ncb = (wid*32 + nt*16 + lhi*4) * 2;
      f16x4 h;
      #pragma unroll
      for (int r = 0; r < 4; ++r) h[r] = (_Float16)fmaxf(acc2[nt][et][r], 0.f);
      *(f16x4*)(smem + e * 512 + (ncb ^ ((e & 7) << 4))) = h;
    }
  __syncthreads();

  f32x4 acc3[2][4];
  #pragma unroll
  for (int nt = 0; nt < 2; ++nt) {
    f32x4 bv = *(const f32x4*)(bls + 768 + wid*32 + nt*16 + lhi*4);
    #pragma unroll
    for (int et = 0; et < 4; ++et) acc3[nt][et] = bv;
  }
  for (int kt = 0; kt < 8; ++kt) {
    f16x8 wf[2], xf[4];
    #pragma unroll
    for (int nt = 0; nt < 2; ++nt)
      wf[nt] = *(const f16x8*)(w3 + (((wid*2 + nt)*8 + kt)*64 + lane) * 8);
    #pragma unroll
    for (int et = 0; et < 4; ++et) {
      int e = et*16 + l15;
      xf[et] = *(const f16x8*)(smem + e * 512 + ((kt*64 + lhi*16) ^ ((e & 7) << 4)));
    }
    #pragma unroll
    for (int nt = 0; nt < 2; ++nt)
      #pragma unroll
      for (int et = 0; et < 4; ++et)
        acc3[nt][et] = __builtin_amdgcn_mfma_f32_16x16x32_f16(wf[nt], xf[et], acc3[nt][et], 0, 0, 0);
  }

  f32x4 w4v[2];
  #pragma unroll
  for (int nt = 0; nt < 2; ++nt)
    w4v[nt] = *(const f32x4*)(bls + 1024 + wid*32 + nt*16 + lhi*4);
  float bias4 = bls[1280];

  #pragma unroll
  for (int et = 0; et < 4; ++et) {
    float p = 0.f;
    #pragma unroll
    for (int nt = 0; nt < 2; ++nt)
      #pragma unroll
      for (int r = 0; r < 4; ++r)
        p += fmaxf(acc3[nt][et][r], 0.f) * w4v[nt][r];
    p += __shfl_xor(p, 16);
    p += __shfl_xor(p, 32);
    if (lane < 16) scr[(et*16 + l15) * 8 + wid] = p;
  }
  __syncthreads();

  if (tid < 64) {
    int ge = base + tid;
    if (ge < E) {
      float s = bias4;
      #pragma unroll
      for (int w = 0; w < 8; ++w) s += scr[tid*8 + w];
      out[ge] = 1.f / (1.f + expf(-s));
    }
  }
}

extern "C" void kernel_launch(void* const* d_in, const int* in_sizes, int n_in,
                              void* d_out, int out_size, void* d_ws, size_t ws_size,
                              hipStream_t stream) {
  const float* z  = (const float*)d_in[0];
  const int*   ei = (const int*)d_in[1];
  const float* W1 = (const float*)d_in[2];
  const float* b1 = (const float*)d_in[3];
  const float* W2 = (const float*)d_in[4];
  const float* b2 = (const float*)d_in[5];
  const float* W3 = (const float*)d_in[6];
  const float* b3 = (const float*)d_in[7];
  const float* W4 = (const float*)d_in[8];
  const float* b4 = (const float*)d_in[9];
  float* out = (float*)d_out;
  const int E = in_sizes[1] / 2;
  const int N = in_sizes[0] / 256;

  _Float16* wbuf = (_Float16*)d_ws;                      // 917504 B
  _Float16* H    = (_Float16*)((char*)d_ws + H_OFF);     // N*1024*2 B

  repack_w<<<(WTOT + 255) / 256, 256, 0, stream>>>(W1, W2, W3, wbuf);

  size_t need = (size_t)H_OFF + (size_t)N * 1024 * 2;
  int nblk = (E + 63) / 64;
  if (ws_size >= need) {
    dim3 pg((N + 63) / 64, 2);
    precompute_h<<<pg, 512, 0, stream>>>(z, N, b1, wbuf, H);
    fused_edges<<<nblk, 512, LDS2_BYTES, stream>>>(ei, E, H, b2, b3, W4, b4,
                                                   wbuf + W1E, wbuf + W1E + W2E, out);
  } else {
    fused_fallback<<<nblk, 512, FLDS_BYTES, stream>>>(z, ei, E, b1, b2, b3, W4, b4, wbuf, out);
  }
}